// Round 4
// baseline (52863.324 us; speedup 1.0000x reference)
//
#include <hip/hip_runtime.h>
#include <math.h>

// Problem constants: N=64, S=512, D=512, C=1024
#define DD 512
#define SS 512
#define NB 64
#define CC 1024
#define FF 2048
#define LN_EPS 1e-5f

__device__ __forceinline__ float sigf(float x) {
  return 1.0f / (1.0f + __expf(-x));
}
__device__ __forceinline__ float geluf(float x) {
  float u = 1.5957691216057308f * (x + 0.044715f * x * x * x);
  return x / (1.0f + __expf(-u));
}

// ---- coherent (MALL-level) access: bypasses per-XCD L2 -------------------
__device__ __forceinline__ float cload(const float* p) {
  return __hip_atomic_load(p, __ATOMIC_RELAXED, __HIP_MEMORY_SCOPE_AGENT);
}
__device__ __forceinline__ unsigned cloadu(const unsigned* p) {
  return __hip_atomic_load(p, __ATOMIC_RELAXED, __HIP_MEMORY_SCOPE_AGENT);
}
__device__ __forceinline__ unsigned long long cload8(
    const unsigned long long* p) {
  return __hip_atomic_load(p, __ATOMIC_RELAXED, __HIP_MEMORY_SCOPE_AGENT);
}
__device__ __forceinline__ void cstore(float* p, float v) {
  __hip_atomic_store(p, v, __ATOMIC_RELAXED, __HIP_MEMORY_SCOPE_AGENT);
}
__device__ __forceinline__ void cstoreu(unsigned* p, unsigned v) {
  __hip_atomic_store(p, v, __ATOMIC_RELAXED, __HIP_MEMORY_SCOPE_AGENT);
}
__device__ __forceinline__ void cstore2(float* p, float a, float b) {
  float2 v = make_float2(a, b);
  unsigned long long u;
  __builtin_memcpy(&u, &v, 8);
  __hip_atomic_store((unsigned long long*)p, u, __ATOMIC_RELAXED,
                     __HIP_MEMORY_SCOPE_AGENT);
}

// ---- fence-free grid barrier: distributed epoch-valued flag array --------
// (round-2 proven version; NO cache maintenance anywhere)
__device__ __forceinline__ void gbar(unsigned* __restrict__ flags,
                                     unsigned ep) {
  asm volatile("s_waitcnt vmcnt(0) lgkmcnt(0)" ::: "memory");
  __syncthreads();
  if (threadIdx.x < 64) {
    if (threadIdx.x == 0)
      cstoreu(&flags[blockIdx.x], ep);
    const unsigned* fp = flags + (threadIdx.x << 2);
    for (;;) {
      unsigned f0 = cloadu(fp + 0);
      unsigned f1 = cloadu(fp + 1);
      unsigned f2 = cloadu(fp + 2);
      unsigned f3 = cloadu(fp + 3);
      int ok = (f0 >= ep) & (f1 >= ep) & (f2 >= ep) & (f3 >= ep);
      if (__all(ok)) break;
      __builtin_amdgcn_s_sleep(1);
    }
  }
  __syncthreads();
}

// ---------------- prologue: seq2 = LN((seq*mask)@W_init+b_init)*mask ------
__global__ __launch_bounds__(256) void k_gemm_init(
    const float* __restrict__ A, const float* __restrict__ mask,
    const float* __restrict__ W, const float* __restrict__ bias,
    float* __restrict__ out) {
  __shared__ float As[16][65];
  __shared__ float Bs[16][65];
  const int tid = threadIdx.x;
  const int bm = blockIdx.y * 64;
  const int bn = blockIdx.x * 64;
  const int tx = tid & 15;
  const int ty = tid >> 4;
  const int idx = tid * 4;
  const int am = idx >> 4;
  const int ak = idx & 15;
  const int bk = idx >> 6;
  const int bn2 = idx & 63;
  const float mrow = mask[bm + am];
  float acc[4][4] = {};
  for (int k0 = 0; k0 < DD; k0 += 16) {
    float4 av = *(const float4*)(A + (size_t)(bm + am) * DD + k0 + ak);
    As[ak + 0][am] = av.x * mrow;
    As[ak + 1][am] = av.y * mrow;
    As[ak + 2][am] = av.z * mrow;
    As[ak + 3][am] = av.w * mrow;
    float4 bv = *(const float4*)(W + (size_t)(k0 + bk) * DD + bn + bn2);
    Bs[bk][bn2 + 0] = bv.x;
    Bs[bk][bn2 + 1] = bv.y;
    Bs[bk][bn2 + 2] = bv.z;
    Bs[bk][bn2 + 3] = bv.w;
    __syncthreads();
#pragma unroll
    for (int kk = 0; kk < 16; ++kk) {
      float a0 = As[kk][ty * 4 + 0], a1 = As[kk][ty * 4 + 1];
      float a2 = As[kk][ty * 4 + 2], a3 = As[kk][ty * 4 + 3];
      float b0 = Bs[kk][tx * 4 + 0], b1v = Bs[kk][tx * 4 + 1];
      float b2v = Bs[kk][tx * 4 + 2], b3 = Bs[kk][tx * 4 + 3];
      acc[0][0] = fmaf(a0, b0, acc[0][0]);
      acc[0][1] = fmaf(a0, b1v, acc[0][1]);
      acc[0][2] = fmaf(a0, b2v, acc[0][2]);
      acc[0][3] = fmaf(a0, b3, acc[0][3]);
      acc[1][0] = fmaf(a1, b0, acc[1][0]);
      acc[1][1] = fmaf(a1, b1v, acc[1][1]);
      acc[1][2] = fmaf(a1, b2v, acc[1][2]);
      acc[1][3] = fmaf(a1, b3, acc[1][3]);
      acc[2][0] = fmaf(a2, b0, acc[2][0]);
      acc[2][1] = fmaf(a2, b1v, acc[2][1]);
      acc[2][2] = fmaf(a2, b2v, acc[2][2]);
      acc[2][3] = fmaf(a2, b3, acc[2][3]);
      acc[3][0] = fmaf(a3, b0, acc[3][0]);
      acc[3][1] = fmaf(a3, b1v, acc[3][1]);
      acc[3][2] = fmaf(a3, b2v, acc[3][2]);
      acc[3][3] = fmaf(a3, b3, acc[3][3]);
    }
    __syncthreads();
  }
#pragma unroll
  for (int i2 = 0; i2 < 4; ++i2) {
    int row = bm + ty * 4 + i2;
#pragma unroll
    for (int j = 0; j < 4; ++j) {
      int col = bn + tx * 4 + j;
      out[(size_t)row * DD + col] = acc[i2][j] + bias[col];
    }
  }
}

__global__ __launch_bounds__(256) void k_ln_rows(
    float* __restrict__ io, const float* __restrict__ mask,
    const float* __restrict__ g, const float* __restrict__ b) {
  const int r = blockIdx.x;
  float* row = io + (size_t)r * DD;
  const int tid = threadIdx.x;
  float x0 = row[tid], x1 = row[tid + 256];
  float s = x0 + x1, ss = x0 * x0 + x1 * x1;
#pragma unroll
  for (int off = 32; off > 0; off >>= 1) {
    s += __shfl_down(s, off, 64);
    ss += __shfl_down(ss, off, 64);
  }
  __shared__ float red[8];
  int lane = tid & 63, wv = tid >> 6;
  if (lane == 0) { red[wv] = s; red[4 + wv] = ss; }
  __syncthreads();
  s = red[0] + red[1] + red[2] + red[3];
  ss = red[4] + red[5] + red[6] + red[7];
  float mean = s * (1.0f / DD);
  float var = ss * (1.0f / DD) - mean * mean;
  float rs = rsqrtf(var + LN_EPS);
  float m = mask[r];
  row[tid] = ((x0 - mean) * rs * g[tid] + b[tid]) * m;
  row[tid + 256] = ((x1 - mean) * rs * g[tid + 256] + b[tid + 256]) * m;
}

// ---- transpose seq2 (n,t,k) -> xT[t][k][n] -------------------------------
__global__ __launch_bounds__(256) void k_xt(const float* __restrict__ seq2,
                                            float* __restrict__ xT) {
  __shared__ float tl[64][65];
  const int t = blockIdx.x;
  const int kt = blockIdx.y * 64;
  const int n = threadIdx.x >> 2;
  const int f = threadIdx.x & 3;
#pragma unroll
  for (int u = 0; u < 4; ++u) {
    int k = f * 16 + u * 4;
    float4 v = *(const float4*)(seq2 + ((size_t)n * SS + t) * DD + kt + k);
    tl[k + 0][n] = v.x;
    tl[k + 1][n] = v.y;
    tl[k + 2][n] = v.z;
    tl[k + 3][n] = v.w;
  }
  __syncthreads();
  const int k2 = threadIdx.x >> 2;
#pragma unroll
  for (int u = 0; u < 4; ++u) {
    int nn = f * 16 + u * 4;
    float4 v = make_float4(tl[k2][nn], tl[k2][nn + 1], tl[k2][nn + 2],
                           tl[k2][nn + 3]);
    *(float4*)(xT + ((size_t)t * DD + kt + k2) * 64 + nn) = v;
  }
}

// ---- pack W1 per block: W1p[b][k][c] = (k<512? g[k]:1) * W1[k][4b+c] ----
__global__ __launch_bounds__(256) void k_pack1(const float* __restrict__ W1,
                                               const float* __restrict__ ln_g,
                                               float* __restrict__ W1p) {
  int i = blockIdx.x * 256 + threadIdx.x;
  int bb = i >> 12;
  int k = (i >> 2) & 1023;
  int c = i & 3;
  float v = W1[(size_t)k * CC + bb * 4 + c];
  if (k < 512) v *= ln_g[k];
  W1p[i] = v;
}

// ---- pack W2 per block: W2p[g][k][q*2+j] = W2[k][q*512+2g+j] -------------
__global__ __launch_bounds__(256) void k_pack2(const float* __restrict__ W2,
                                               float* __restrict__ W2p) {
  int i = blockIdx.x * 256 + threadIdx.x;
  int g = i >> 13;
  int k = (i >> 3) & 1023;
  int q = (i >> 1) & 3;
  int j = i & 1;
  W2p[i] = W2[(size_t)k * FF + q * 512 + 2 * g + j];
}

// ---- column sums + zero sync words ---------------------------------------
__global__ __launch_bounds__(128) void k_cols(
    const float* __restrict__ W1, const float* __restrict__ b1,
    const float* __restrict__ ln_g, const float* __restrict__ ln_b,
    const float* __restrict__ START, float* __restrict__ Qc,
    float* __restrict__ Blnc, float* __restrict__ H0c,
    unsigned* __restrict__ sync) {
  int c = blockIdx.x * 128 + threadIdx.x;
  sync[c] = 0u;          // grid flags, xcd counters, xcd flags ...
  sync[c + 1024] = 0u;   // ... (2048 words total)
  float q = 0.f, bl = 0.f, h = 0.f;
  for (int k = 0; k < 512; ++k) {
    float wv = W1[(size_t)k * CC + c];
    q = fmaf(ln_g[k], wv, q);
    bl = fmaf(ln_b[k], wv, bl);
    h = fmaf(START[k], wv, h);
  }
  float bias = b1[c];
  Qc[c] = q;
  Blnc[c] = bl + bias;
  H0c[c] = h + bias;
}

// ---------------- persistent scan (plain launch, 256x512) -----------------
// Per-XCD replication: after each grid barrier, the blocks of each physical
// XCD (s_getreg XCC_ID) cooperatively copy zT/interT (agent loads from MALL,
// 1/32 slice each) into a per-XCD replica written with NORMAL stores (dirty
// lines in the local L2 — never read cross-XCD, never invalidated). A
// lightweight intra-XCD flag barrier orders stage->consume; consumption is
// plain cached loads served by the local L2. No cache-maintenance ops.
__global__ __launch_bounds__(512, 1) void scan_kernel(
    float* __restrict__ outseq, float* __restrict__ gsout,
    const float* __restrict__ mask, const float* __restrict__ START,
    const float* __restrict__ W1p, const float* __restrict__ W2p,
    const float* __restrict__ b2, const float* __restrict__ ln_g,
    const float* __restrict__ ln_b, const float* __restrict__ Qc,
    const float* __restrict__ Blnc, const float* __restrict__ H0c,
    float* __restrict__ interT, float* __restrict__ zT,
    float* __restrict__ st_sum, float* __restrict__ st_ss,
    const float* __restrict__ xT, unsigned* __restrict__ sync,
    float* __restrict__ xbufZ, float* __restrict__ xbufI,
    const int use_xt, const int use_stage) {
  const int b = blockIdx.x;
  const int tid = threadIdx.x;
  const int w = tid >> 6;
  const int lane = tid & 63;
  const int d0 = 2 * b;
  unsigned ep = 0;

  __shared__ float4 pA4[8][64];
  __shared__ float4 pB4[8][64][2];
  __shared__ float W1s[4096];  // this block's W1p slice (16 KB)
  __shared__ float W2s[8192];  // this block's W2p slice (32 KB)
  __shared__ unsigned sh_slot;

  // physical XCD id (uniform per block)
  unsigned xcd_raw;
  asm("s_getreg_b32 %0, hwreg(20, 0, 4)" : "=s"(xcd_raw));
  const int xcd = (int)(xcd_raw & 7u);
  unsigned* const zf = sync + 320 + (xcd << 6);   // z-replica flags
  unsigned* const ifl = sync + 832 + (xcd << 6);  // inter-replica flags
  float* const myZ = xbufZ + ((size_t)xcd << 15);
  float* const myI = xbufI + ((size_t)xcd << 16);

  // per-XCD ticket -> staging slot (robust to any block->XCD distribution)
  if (tid == 0)
    sh_slot = __hip_atomic_fetch_add(&sync[256 + xcd], 1u, __ATOMIC_RELAXED,
                                     __HIP_MEMORY_SCOPE_AGENT);

  // stage weights to LDS once
  {
    const float4* w1src = (const float4*)(W1p + ((size_t)b << 12));
    const float4* w2src = (const float4*)(W2p + ((size_t)b << 13));
#pragma unroll
    for (int i = 0; i < 2; ++i)
      ((float4*)W1s)[tid + 512 * i] = w1src[tid + 512 * i];
#pragma unroll
    for (int i = 0; i < 4; ++i)
      ((float4*)W2s)[tid + 512 * i] = w2src[tid + 512 * i];
  }

  float ht0 = 0, ht1 = 0, gs0 = 0, gs1 = 0, z0 = 0, z1 = 0;
  float gg0 = 0, gg1 = 0, bb0 = 0, bb1 = 0, mn = 0, rv = 0;
  if (tid < 64) {
    ht0 = START[d0];
    ht1 = START[d0 + 1];
    gs0 = ht0;
    gs1 = ht1;
    gg0 = ln_g[d0];
    gg1 = ln_g[d0 + 1];
    bb0 = ln_b[d0];
    bb1 = ln_b[d0 + 1];
  }
  const float4 Q4 = *(const float4*)(Qc + 4 * b);
  const float4 Bl4 = *(const float4*)(Blnc + 4 * b);
  const float4 H04 = *(const float4*)(H0c + 4 * b);
  float bb2[8];
#pragma unroll
  for (int q = 0; q < 4; ++q) {
    bb2[2 * q] = b2[q * 512 + d0];
    bb2[2 * q + 1] = b2[q * 512 + d0 + 1];
  }
  __syncthreads();  // weights staged + sh_slot valid
  const int myslot = (int)sh_slot;
  int nblk = 0;  // blocks on this XCD; final after first grid barrier

  for (int t = 0; t < SS; ++t) {
    // ---------- stage z-replica (agent load 1/32 slice, normal store) -----
    if (use_stage && t > 0) {
      for (int c = myslot; c < 32; c += nblk) {
        const unsigned long long* s8 =
            (const unsigned long long*)(zT + (c << 10)) + tid;
        unsigned long long* d8 =
            (unsigned long long*)(myZ + (c << 10)) + tid;
        *d8 = cload8(s8);
      }
    }
    // ---------- A-head: finalize step t-1 (owners) ------------------------
    if (t > 0 && tid < 64) {
      const int par9 = ((t - 1) & 1) << 9;
      const float* sp = st_sum + par9 + (tid << 3);
      const float* qp = st_ss + par9 + (tid << 3);
      float s = 0.f, ss = 0.f;
#pragma unroll
      for (int i = 0; i < 8; ++i) {
        s += cload(sp + i);
        ss += cload(qp + i);
      }
      float mean = s * (1.0f / DD);
      float var = ss * (1.0f / DD) - mean * mean;
      float rsv = rsqrtf(var + LN_EPS);
      mn = mean;
      rv = rsv;
      float hn0 = (z0 - mean) * rsv * gg0 + bb0;
      float hn1 = (z1 - mean) * rsv * gg1 + bb1;
      float m = mask[tid * SS + (t - 1)];
      float* op = outseq + (size_t)tid * SS * DD + (size_t)(t - 1) * DD + d0;
      if (use_xt) {
        *(float2*)op = make_float2(hn0 * m, hn1 * m);  // output-only: plain
      } else {
        cstore2(op, hn0 * m, hn1 * m);  // read cross-block in fallback
      }
      gs0 = m * hn0 + (1.0f - m) * gs0;
      gs1 = m * hn1 + (1.0f - m) * gs1;
      ht0 = hn0;
      ht1 = hn1;
    }
    if (b == 0) {  // zero stats parity t&1 (used by B(t) after barrier 1)
      const int parz9 = (t & 1) << 9;
      cstore(st_sum + parz9 + tid, 0.f);
      cstore(st_ss + parz9 + tid, 0.f);
    }
    if (use_stage && t > 0) {
      __syncthreads();  // all staging stores drained (vmcnt0 at barrier)
      if (tid == 0) cstoreu(zf + (myslot < 63 ? myslot : 63), (unsigned)t);
    }
    // ---------- A waves: gemm1 partials -----------------------------------
    {
      const int k0 = w << 7;
      float4 acc = make_float4(0.f, 0.f, 0.f, 0.f);
      const float* wp = W1s + (k0 << 2);
      if (w < 4) {
        if (t > 0) {  // z-part
          if (use_stage) {
            // wait for this XCD's z-replica (overlaps waves 4-7 x-part)
            const int lim = nblk < 32 ? nblk : 32;
            for (;;) {
              int ok = 1;
              for (int s = lane; s < lim; s += 64)
                ok &= (int)(cloadu(zf + s) >= (unsigned)t);
              if (__all(ok)) break;
              __builtin_amdgcn_s_sleep(1);
            }
            asm volatile("" ::: "memory");
            const float* ap = myZ + k0 * 64 + lane;  // local-L2 cached
            for (int c0 = 0; c0 < 128; c0 += 64) {
              float v[64];
#pragma unroll
              for (int j = 0; j < 64; ++j) v[j] = ap[(c0 + j) << 6];
#pragma unroll
              for (int j = 0; j < 64; ++j) {
                const float* wr = wp + ((c0 + j) << 2);
                acc.x = fmaf(v[j], wr[0], acc.x);
                acc.y = fmaf(v[j], wr[1], acc.y);
                acc.z = fmaf(v[j], wr[2], acc.z);
                acc.w = fmaf(v[j], wr[3], acc.w);
              }
            }
          } else {  // fallback: direct MALL loads
            const float* ap = zT + k0 * 64 + lane;
            for (int c0 = 0; c0 < 128; c0 += 64) {
              float v[64];
#pragma unroll
              for (int j = 0; j < 64; ++j) v[j] = cload(ap + ((c0 + j) << 6));
#pragma unroll
              for (int j = 0; j < 64; ++j) {
                const float* wr = wp + ((c0 + j) << 2);
                acc.x = fmaf(v[j], wr[0], acc.x);
                acc.y = fmaf(v[j], wr[1], acc.y);
                acc.z = fmaf(v[j], wr[2], acc.z);
                acc.w = fmaf(v[j], wr[3], acc.w);
              }
            }
          }
        }
      } else {
        const int kx = k0 - 512;
        if (use_xt) {  // x-part: read-only prologue data, cached loads
          const float* xp = xT + ((size_t)t * DD + kx) * 64 + lane;
          for (int c0 = 0; c0 < 128; c0 += 64) {
            float v[64];
#pragma unroll
            for (int j = 0; j < 64; ++j) v[j] = xp[(c0 + j) << 6];
#pragma unroll
            for (int j = 0; j < 64; ++j) {
              const float* wr = wp + ((c0 + j) << 2);
              acc.x = fmaf(v[j], wr[0], acc.x);
              acc.y = fmaf(v[j], wr[1], acc.y);
              acc.z = fmaf(v[j], wr[2], acc.z);
              acc.w = fmaf(v[j], wr[3], acc.w);
            }
          }
        } else {
          const float* op =
              outseq + (size_t)lane * SS * DD + (size_t)t * DD + kx;
          for (int c0 = 0; c0 < 128; c0 += 16) {
            float4 xv[4];
#pragma unroll
            for (int j = 0; j < 4; ++j)
              xv[j] = *(const float4*)(op + c0 + 4 * j);
#pragma unroll
            for (int j = 0; j < 16; ++j) {
              const float* wr = wp + ((c0 + j) << 2);
              float x = ((const float*)xv)[j];
              acc.x = fmaf(x, wr[0], acc.x);
              acc.y = fmaf(x, wr[1], acc.y);
              acc.z = fmaf(x, wr[2], acc.z);
              acc.w = fmaf(x, wr[3], acc.w);
            }
          }
        }
      }
      pA4[w][lane] = acc;
    }
    __syncthreads();
    // ---------- A-tail: epilogue (LN fold) + gelu -> interT (coherent) ----
    if (tid < 64) {
      float4 P = pA4[0][tid];
      float4 X = pA4[4][tid];
#pragma unroll
      for (int ww = 1; ww < 4; ++ww) {
        float4 p = pA4[ww][tid];
        P.x += p.x; P.y += p.y; P.z += p.z; P.w += p.w;
        float4 x4 = pA4[ww + 4][tid];
        X.x += x4.x; X.y += x4.y; X.z += x4.z; X.w += x4.w;
      }
      float4 o;
      if (t > 0) {
        float c1 = -rv * mn;
        o.x = fmaf(rv, P.x, fmaf(c1, Q4.x, Bl4.x)) + X.x;
        o.y = fmaf(rv, P.y, fmaf(c1, Q4.y, Bl4.y)) + X.y;
        o.z = fmaf(rv, P.z, fmaf(c1, Q4.z, Bl4.z)) + X.z;
        o.w = fmaf(rv, P.w, fmaf(c1, Q4.w, Bl4.w)) + X.w;
      } else {
        o.x = H04.x + X.x;
        o.y = H04.y + X.y;
        o.z = H04.z + X.z;
        o.w = H04.w + X.w;
      }
      cstore(interT + (4 * b + 0) * 64 + tid, geluf(o.x));
      cstore(interT + (4 * b + 1) * 64 + tid, geluf(o.y));
      cstore(interT + (4 * b + 2) * 64 + tid, geluf(o.z));
      cstore(interT + (4 * b + 3) * 64 + tid, geluf(o.w));
    }
    gbar(sync, ++ep);  // barrier 1: interT visible at MALL
    if (t == 0) nblk = (int)cloadu(&sync[256 + xcd]);  // counts final now
    // ---------- stage inter-replica + intra-XCD barrier -------------------
    if (use_stage) {
      for (int c = myslot; c < 32; c += nblk) {
        const unsigned long long* s8 =
            (const unsigned long long*)(interT + (c << 11)) + tid;
        unsigned long long* d8 =
            (unsigned long long*)(myI + (c << 11)) + tid;
        unsigned long long a0 = cload8(s8);
        unsigned long long a1 = cload8(s8 + 512);
        d8[0] = a0;
        d8[512] = a1;
      }
      __syncthreads();  // staging stores drained
      if (tid == 0)
        cstoreu(ifl + (myslot < 63 ? myslot : 63), (unsigned)(t + 1));
      const int lim = nblk < 32 ? nblk : 32;
      for (;;) {
        int ok = 1;
        for (int s = lane; s < lim; s += 64)
          ok &= (int)(cloadu(ifl + s) >= (unsigned)(t + 1));
        if (__all(ok)) break;
        __builtin_amdgcn_s_sleep(1);
      }
      asm volatile("" ::: "memory");
    }
    // ---------- B waves: gemm2 partials ------------------------------------
    {
      const int k0 = w << 7;
      float4 accL = make_float4(0.f, 0.f, 0.f, 0.f);
      float4 accH = make_float4(0.f, 0.f, 0.f, 0.f);
      const float* w2 = W2s + (k0 << 3);
      if (use_stage) {
        const float* ip = myI + k0 * 64 + lane;  // local-L2 cached
        for (int c0 = 0; c0 < 128; c0 += 64) {
          float v[64];
#pragma unroll
          for (int j = 0; j < 64; ++j) v[j] = ip[(c0 + j) << 6];
#pragma unroll
          for (int j = 0; j < 64; ++j) {
            const float* wr = w2 + ((c0 + j) << 3);
            accL.x = fmaf(v[j], wr[0], accL.x);
            accL.y = fmaf(v[j], wr[1], accL.y);
            accL.z = fmaf(v[j], wr[2], accL.z);
            accL.w = fmaf(v[j], wr[3], accL.w);
            accH.x = fmaf(v[j], wr[4], accH.x);
            accH.y = fmaf(v[j], wr[5], accH.y);
            accH.z = fmaf(v[j], wr[6], accH.z);
            accH.w = fmaf(v[j], wr[7], accH.w);
          }
        }
      } else {
        const float* ip = interT + k0 * 64 + lane;
        for (int c0 = 0; c0 < 128; c0 += 64) {
          float v[64];
#pragma unroll
          for (int j = 0; j < 64; ++j) v[j] = cload(ip + ((c0 + j) << 6));
#pragma unroll
          for (int j = 0; j < 64; ++j) {
            const float* wr = w2 + ((c0 + j) << 3);
            accL.x = fmaf(v[j], wr[0], accL.x);
            accL.y = fmaf(v[j], wr[1], accL.y);
            accL.z = fmaf(v[j], wr[2], accL.z);
            accL.w = fmaf(v[j], wr[3], accL.w);
            accH.x = fmaf(v[j], wr[4], accH.x);
            accH.y = fmaf(v[j], wr[5], accH.y);
            accH.z = fmaf(v[j], wr[6], accH.z);
            accH.w = fmaf(v[j], wr[7], accH.w);
          }
        }
      }
      pB4[w][lane][0] = accL;
      pB4[w][lane][1] = accH;
    }
    __syncthreads();
    // ---------- B-tail: gates -> z (coherent), stats atomics --------------
    if (tid < 64) {
      float4 lo = pB4[0][tid][0];
      float4 hi = pB4[0][tid][1];
#pragma unroll
      for (int ww = 1; ww < 8; ++ww) {
        float4 p = pB4[ww][tid][0];
        lo.x += p.x; lo.y += p.y; lo.z += p.z; lo.w += p.w;
        float4 q = pB4[ww][tid][1];
        hi.x += q.x; hi.y += q.y; hi.z += q.z; hi.w += q.w;
      }
      lo.x += bb2[0]; lo.y += bb2[1]; lo.z += bb2[2]; lo.w += bb2[3];
      hi.x += bb2[4]; hi.y += bb2[5]; hi.z += bb2[6]; hi.w += bb2[7];
      float x0, x1;
      if (use_xt) {
        x0 = xT[((size_t)t * DD + d0) * 64 + tid];
        x1 = xT[((size_t)t * DD + d0 + 1) * 64 + tid];
      } else {
        float2 x2 = *(const float2*)(outseq + (size_t)tid * SS * DD +
                                     (size_t)t * DD + d0);
        x0 = x2.x;
        x1 = x2.y;
      }
      z0 = sigf(lo.x) * ht0 + sigf(lo.z) * x0 + sigf(hi.x) * hi.z;
      z1 = sigf(lo.y) * ht1 + sigf(lo.w) * x1 + sigf(hi.y) * hi.w;
      cstore(zT + d0 * 64 + tid, z0);
      cstore(zT + (d0 + 1) * 64 + tid, z1);
      const int par9 = (t & 1) << 9;
      const int slot = b & 7;
      atomicAdd(st_sum + par9 + (tid << 3) + slot, z0 + z1);
      atomicAdd(st_ss + par9 + (tid << 3) + slot, z0 * z0 + z1 * z1);
    }
    gbar(sync, ++ep);  // barrier 2: z + stats visible at MALL
  }
  // ---------- flush step 511 ----------
  if (tid < 64) {
    const int par9 = ((SS - 1) & 1) << 9;
    const float* sp = st_sum + par9 + (tid << 3);
    const float* qp = st_ss + par9 + (tid << 3);
    float s = 0.f, ss = 0.f;
#pragma unroll
    for (int i = 0; i < 8; ++i) {
      s += cload(sp + i);
      ss += cload(qp + i);
    }
    float mean = s * (1.0f / DD);
    float var = ss * (1.0f / DD) - mean * mean;
    float rsv = rsqrtf(var + LN_EPS);
    float hn0 = (z0 - mean) * rsv * gg0 + bb0;
    float hn1 = (z1 - mean) * rsv * gg1 + bb1;
    float m = mask[tid * SS + (SS - 1)];
    *(float2*)(outseq + (size_t)tid * SS * DD + (size_t)(SS - 1) * DD + d0) =
        make_float2(hn0 * m, hn1 * m);
    gs0 = m * hn0 + (1.0f - m) * gs0;
    gs1 = m * hn1 + (1.0f - m) * gs1;
    *(float2*)(gsout + tid * DD + d0) = make_float2(gs0, gs1);
  }
}

// ---------------- host ----------------------------------------------------
extern "C" void kernel_launch(void* const* d_in, const int* in_sizes, int n_in,
                              void* d_out, int out_size, void* d_ws,
                              size_t ws_size, hipStream_t stream) {
  const float* seq = (const float*)d_in[0];
  const float* mask = (const float*)d_in[1];
  const float* START = (const float*)d_in[2];
  const float* W_init = (const float*)d_in[3];
  const float* b_init = (const float*)d_in[4];
  const float* W1 = (const float*)d_in[5];
  const float* b1 = (const float*)d_in[6];
  const float* W2 = (const float*)d_in[7];
  const float* b2 = (const float*)d_in[8];
  const float* ln_g = (const float*)d_in[9];
  const float* ln_b = (const float*)d_in[10];

  float* out = (float*)d_out;
  float* outseq = out;
  float* gsout = out + (size_t)NB * SS * DD;

  float* W1p = (float*)d_ws;              // 1,048,576
  float* W2p = W1p + 1048576;             // 2,097,152
  float* interT = W2p + 2097152;          // 65,536
  float* zT = interT + 65536;             // 32,768
  float* st_sum = zT + 32768;             // 4,096 (uses [2][64][8])
  float* st_ss = st_sum + 4096;           // 4,096
  float* Qc = st_ss + 4096;               // 1,024
  float* Blnc = Qc + 1024;                // 1,024
  float* H0c = Blnc + 1024;               // 1,024
  unsigned* syncw = (unsigned*)(H0c + 1024);  // 2,048 u32
  float* xT = (float*)(syncw + 2048);     // 16,777,216 (optional)
  float* xbufZ = xT + 16777216;           // 262,144 (8 XCD z replicas)
  float* xbufI = xbufZ + 262144;          // 524,288 (8 XCD inter replicas)

  const size_t pre_xt = 1048576 + 2097152 + 65536 + 32768 + 4096 + 4096 +
                        1024 + 1024 + 1024 + 2048;
  const int use_xt = (ws_size >= (pre_xt + (size_t)16777216) * 4) ? 1 : 0;
  const int use_stage =
      (use_xt &&
       ws_size >= (pre_xt + (size_t)16777216 + 262144 + 524288) * 4)
          ? 1
          : 0;

  dim3 ga(DD / 64, (NB * SS) / 64);
  k_gemm_init<<<ga, 256, 0, stream>>>(seq, mask, W_init, b_init, outseq);
  k_ln_rows<<<NB * SS, 256, 0, stream>>>(outseq, mask, ln_g, ln_b);
  if (use_xt) {
    k_xt<<<dim3(SS, 8), 256, 0, stream>>>(outseq, xT);
  }
  k_pack1<<<4096, 256, 0, stream>>>(W1, ln_g, W1p);
  k_pack2<<<8192, 256, 0, stream>>>(W2, W2p);
  k_cols<<<8, 128, 0, stream>>>(W1, b1, ln_g, ln_b, START, Qc, Blnc, H0c,
                                syncw);

  scan_kernel<<<256, 512, 0, stream>>>(outseq, gsout, mask, START, W1p, W2p,
                                       b2, ln_g, ln_b, Qc, Blnc, H0c, interT,
                                       zT, st_sum, st_ss, xT, syncw, xbufZ,
                                       xbufI, use_xt, use_stage);
}

// Round 5
// 18120.665 us; speedup vs baseline: 2.9173x; 2.9173x over previous
//
#include <hip/hip_runtime.h>
#include <math.h>

// Problem constants: N=64, S=512, D=512, C=1024
#define DD 512
#define SS 512
#define NB 64
#define CC 1024
#define FF 2048
#define LN_EPS 1e-5f

__device__ __forceinline__ float sigf(float x) {
  return 1.0f / (1.0f + __expf(-x));
}
__device__ __forceinline__ float geluf(float x) {
  float u = 1.5957691216057308f * (x + 0.044715f * x * x * x);
  return x / (1.0f + __expf(-u));
}

// ---- coherent (MALL-level) access: bypasses per-XCD L2 -------------------
__device__ __forceinline__ float cload(const float* p) {
  return __hip_atomic_load(p, __ATOMIC_RELAXED, __HIP_MEMORY_SCOPE_AGENT);
}
__device__ __forceinline__ unsigned cloadu(const unsigned* p) {
  return __hip_atomic_load(p, __ATOMIC_RELAXED, __HIP_MEMORY_SCOPE_AGENT);
}
__device__ __forceinline__ unsigned long long cload8(
    const unsigned long long* p) {
  return __hip_atomic_load(p, __ATOMIC_RELAXED, __HIP_MEMORY_SCOPE_AGENT);
}
__device__ __forceinline__ void cstore(float* p, float v) {
  __hip_atomic_store(p, v, __ATOMIC_RELAXED, __HIP_MEMORY_SCOPE_AGENT);
}
__device__ __forceinline__ void cstoreu(unsigned* p, unsigned v) {
  __hip_atomic_store(p, v, __ATOMIC_RELAXED, __HIP_MEMORY_SCOPE_AGENT);
}
__device__ __forceinline__ void cstore2(float* p, float a, float b) {
  float2 v = make_float2(a, b);
  unsigned long long u;
  __builtin_memcpy(&u, &v, 8);
  __hip_atomic_store((unsigned long long*)p, u, __ATOMIC_RELAXED,
                     __HIP_MEMORY_SCOPE_AGENT);
}
__device__ __forceinline__ float2 u2f2(unsigned long long u) {
  float2 f;
  __builtin_memcpy(&f, &u, 8);
  return f;
}

// ---- fence-free grid barrier: distributed epoch-valued flag array --------
// (round-2 proven version; NO cache maintenance anywhere)
__device__ __forceinline__ void gbar(unsigned* __restrict__ flags,
                                     unsigned ep) {
  asm volatile("s_waitcnt vmcnt(0) lgkmcnt(0)" ::: "memory");
  __syncthreads();
  if (threadIdx.x < 64) {
    if (threadIdx.x == 0) cstoreu(&flags[blockIdx.x], ep);
    const unsigned* fp = flags + (threadIdx.x << 2);
    for (;;) {
      unsigned f0 = cloadu(fp + 0);
      unsigned f1 = cloadu(fp + 1);
      unsigned f2 = cloadu(fp + 2);
      unsigned f3 = cloadu(fp + 3);
      int ok = (f0 >= ep) & (f1 >= ep) & (f2 >= ep) & (f3 >= ep);
      if (__all(ok)) break;
      __builtin_amdgcn_s_sleep(1);
    }
  }
  __syncthreads();
}

// ---------------- prologue: seq2 = LN((seq*mask)@W_init+b_init)*mask ------
__global__ __launch_bounds__(256) void k_gemm_init(
    const float* __restrict__ A, const float* __restrict__ mask,
    const float* __restrict__ W, const float* __restrict__ bias,
    float* __restrict__ out) {
  __shared__ float As[16][65];
  __shared__ float Bs[16][65];
  const int tid = threadIdx.x;
  const int bm = blockIdx.y * 64;
  const int bn = blockIdx.x * 64;
  const int tx = tid & 15;
  const int ty = tid >> 4;
  const int idx = tid * 4;
  const int am = idx >> 4;
  const int ak = idx & 15;
  const int bk = idx >> 6;
  const int bn2 = idx & 63;
  const float mrow = mask[bm + am];
  float acc[4][4] = {};
  for (int k0 = 0; k0 < DD; k0 += 16) {
    float4 av = *(const float4*)(A + (size_t)(bm + am) * DD + k0 + ak);
    As[ak + 0][am] = av.x * mrow;
    As[ak + 1][am] = av.y * mrow;
    As[ak + 2][am] = av.z * mrow;
    As[ak + 3][am] = av.w * mrow;
    float4 bv = *(const float4*)(W + (size_t)(k0 + bk) * DD + bn + bn2);
    Bs[bk][bn2 + 0] = bv.x;
    Bs[bk][bn2 + 1] = bv.y;
    Bs[bk][bn2 + 2] = bv.z;
    Bs[bk][bn2 + 3] = bv.w;
    __syncthreads();
#pragma unroll
    for (int kk = 0; kk < 16; ++kk) {
      float a0 = As[kk][ty * 4 + 0], a1 = As[kk][ty * 4 + 1];
      float a2 = As[kk][ty * 4 + 2], a3 = As[kk][ty * 4 + 3];
      float b0 = Bs[kk][tx * 4 + 0], b1v = Bs[kk][tx * 4 + 1];
      float b2v = Bs[kk][tx * 4 + 2], b3 = Bs[kk][tx * 4 + 3];
      acc[0][0] = fmaf(a0, b0, acc[0][0]);
      acc[0][1] = fmaf(a0, b1v, acc[0][1]);
      acc[0][2] = fmaf(a0, b2v, acc[0][2]);
      acc[0][3] = fmaf(a0, b3, acc[0][3]);
      acc[1][0] = fmaf(a1, b0, acc[1][0]);
      acc[1][1] = fmaf(a1, b1v, acc[1][1]);
      acc[1][2] = fmaf(a1, b2v, acc[1][2]);
      acc[1][3] = fmaf(a1, b3, acc[1][3]);
      acc[2][0] = fmaf(a2, b0, acc[2][0]);
      acc[2][1] = fmaf(a2, b1v, acc[2][1]);
      acc[2][2] = fmaf(a2, b2v, acc[2][2]);
      acc[2][3] = fmaf(a2, b3, acc[2][3]);
      acc[3][0] = fmaf(a3, b0, acc[3][0]);
      acc[3][1] = fmaf(a3, b1v, acc[3][1]);
      acc[3][2] = fmaf(a3, b2v, acc[3][2]);
      acc[3][3] = fmaf(a3, b3, acc[3][3]);
    }
    __syncthreads();
  }
#pragma unroll
  for (int i2 = 0; i2 < 4; ++i2) {
    int row = bm + ty * 4 + i2;
#pragma unroll
    for (int j = 0; j < 4; ++j) {
      int col = bn + tx * 4 + j;
      out[(size_t)row * DD + col] = acc[i2][j] + bias[col];
    }
  }
}

__global__ __launch_bounds__(256) void k_ln_rows(
    float* __restrict__ io, const float* __restrict__ mask,
    const float* __restrict__ g, const float* __restrict__ b) {
  const int r = blockIdx.x;
  float* row = io + (size_t)r * DD;
  const int tid = threadIdx.x;
  float x0 = row[tid], x1 = row[tid + 256];
  float s = x0 + x1, ss = x0 * x0 + x1 * x1;
#pragma unroll
  for (int off = 32; off > 0; off >>= 1) {
    s += __shfl_down(s, off, 64);
    ss += __shfl_down(ss, off, 64);
  }
  __shared__ float red[8];
  int lane = tid & 63, wv = tid >> 6;
  if (lane == 0) { red[wv] = s; red[4 + wv] = ss; }
  __syncthreads();
  s = red[0] + red[1] + red[2] + red[3];
  ss = red[4] + red[5] + red[6] + red[7];
  float mean = s * (1.0f / DD);
  float var = ss * (1.0f / DD) - mean * mean;
  float rs = rsqrtf(var + LN_EPS);
  float m = mask[r];
  row[tid] = ((x0 - mean) * rs * g[tid] + b[tid]) * m;
  row[tid + 256] = ((x1 - mean) * rs * g[tid + 256] + b[tid + 256]) * m;
}

// ---- transpose seq2 (n,t,k) -> xT[t][k][n] -------------------------------
__global__ __launch_bounds__(256) void k_xt(const float* __restrict__ seq2,
                                            float* __restrict__ xT) {
  __shared__ float tl[64][65];
  const int t = blockIdx.x;
  const int kt = blockIdx.y * 64;
  const int n = threadIdx.x >> 2;
  const int f = threadIdx.x & 3;
#pragma unroll
  for (int u = 0; u < 4; ++u) {
    int k = f * 16 + u * 4;
    float4 v = *(const float4*)(seq2 + ((size_t)n * SS + t) * DD + kt + k);
    tl[k + 0][n] = v.x;
    tl[k + 1][n] = v.y;
    tl[k + 2][n] = v.z;
    tl[k + 3][n] = v.w;
  }
  __syncthreads();
  const int k2 = threadIdx.x >> 2;
#pragma unroll
  for (int u = 0; u < 4; ++u) {
    int nn = f * 16 + u * 4;
    float4 v = make_float4(tl[k2][nn], tl[k2][nn + 1], tl[k2][nn + 2],
                           tl[k2][nn + 3]);
    *(float4*)(xT + ((size_t)t * DD + kt + k2) * 64 + nn) = v;
  }
}

// ---- pack W1 per bcol: W1p[bcol][k][c] = (k<512? g[k]:1)*W1[k][8bcol+c] --
__global__ __launch_bounds__(256) void k_pack1(const float* __restrict__ W1,
                                               const float* __restrict__ ln_g,
                                               float* __restrict__ W1p) {
  int i = blockIdx.x * 256 + threadIdx.x;
  int bcol = i >> 13;
  int k = (i >> 3) & 1023;
  int c = i & 7;
  float v = W1[(size_t)k * CC + (bcol << 3) + c];
  if (k < 512) v *= ln_g[k];
  W1p[i] = v;
}

// ---- pack W2 per bcol: W2p[bcol][k][dd*4+q] = W2[k][q*512+4bcol+dd] ------
__global__ __launch_bounds__(256) void k_pack2(const float* __restrict__ W2,
                                               float* __restrict__ W2p) {
  int i = blockIdx.x * 256 + threadIdx.x;
  int bcol = i >> 14;
  int k = (i >> 4) & 1023;
  int j = i & 15;
  int q = j & 3;
  int dd = j >> 2;
  W2p[i] = W2[(size_t)k * FF + q * 512 + (bcol << 2) + dd];
}

// ---- column sums + zero sync words ---------------------------------------
__global__ __launch_bounds__(128) void k_cols(
    const float* __restrict__ W1, const float* __restrict__ b1,
    const float* __restrict__ ln_g, const float* __restrict__ ln_b,
    const float* __restrict__ START, float* __restrict__ Qc,
    float* __restrict__ Blnc, float* __restrict__ H0c,
    unsigned* __restrict__ sync) {
  int c = blockIdx.x * 128 + threadIdx.x;
  sync[c] = 0u;  // zeroes all 256 barrier flags (+ spares)
  float q = 0.f, bl = 0.f, h = 0.f;
  for (int k = 0; k < 512; ++k) {
    float wv = W1[(size_t)k * CC + c];
    q = fmaf(ln_g[k], wv, q);
    bl = fmaf(ln_b[k], wv, bl);
    h = fmaf(START[k], wv, h);
  }
  float bias = b1[c];
  Qc[c] = q;
  Blnc[c] = bl + bias;
  H0c[c] = h + bias;
}

// ---------------- persistent scan: batch-split G=2 (256x512) --------------
// Block (bcol 0..127, bhalf 0..1): owns gemm1 cols [8bcol,8bcol+8),
// gemm2 cols {q*512 + 4bcol + dd}, recurrence dims [4bcol,4bcol+4), for
// batches [32*bhalf, 32*bhalf+32). Shared-state reads per block are HALVED
// vs the batch=lanes layout (z: 64KB, inter: 128KB). zT/interT use k-paired
// layout [k/2][n][2] so each agent load is 8B and wave requests stay at
// 256B of distinct data. Owner lanes tid<64: batch = 32*bhalf + (tid&31),
// dim pair dbase = 4*bcol + 2*(tid>>5).
__global__ __launch_bounds__(512, 1) void scan_kernel(
    float* __restrict__ outseq, float* __restrict__ gsout,
    const float* __restrict__ mask, const float* __restrict__ START,
    const float* __restrict__ W1p, const float* __restrict__ W2p,
    const float* __restrict__ b2, const float* __restrict__ ln_g,
    const float* __restrict__ ln_b, const float* __restrict__ Qc,
    const float* __restrict__ Blnc, const float* __restrict__ H0c,
    float* __restrict__ interT, float* __restrict__ zT,
    float* __restrict__ st_sum, float* __restrict__ st_ss,
    const float* __restrict__ xT, unsigned* __restrict__ sync,
    const int use_xt) {
  const int b = blockIdx.x;
  const int bcol = b >> 1;
  const int bhalf = b & 1;
  const int tid = threadIdx.x;
  const int w = tid >> 6;
  const int lane = tid & 63;
  unsigned ep = 0;

  __shared__ float4 pA4[8][64];
  __shared__ float4 pB4[8][64][2];
  __shared__ float W1s[8192];   // [k 0..1023][c 0..7]   (32 KB)
  __shared__ float W2s[16384];  // [k 0..1023][j 0..15]  (64 KB)

  // stage weights to LDS once (prologue-written, visible at dispatch start)
  {
    const float4* w1src = (const float4*)(W1p + ((size_t)bcol << 13));
    const float4* w2src = (const float4*)(W2p + ((size_t)bcol << 14));
#pragma unroll
    for (int i = 0; i < 4; ++i)
      ((float4*)W1s)[tid + 512 * i] = w1src[tid + 512 * i];
#pragma unroll
    for (int i = 0; i < 8; ++i)
      ((float4*)W2s)[tid + 512 * i] = w2src[tid + 512 * i];
  }

  // owner-lane state (tid<64): batch n, dim pair dbase..dbase+1
  const int on = (bhalf << 5) + (tid & 31);       // global batch
  const int oh = tid >> 5;                        // 0/1: which dim pair
  const int dbase = (bcol << 2) + (oh << 1);      // global dim (even)
  const int colbase = (bcol << 3) + (oh << 2);    // gemm1 col base (A-tail)
  float ht0 = 0, ht1 = 0, gs0 = 0, gs1 = 0, z0 = 0, z1 = 0;
  float gg0 = 0, gg1 = 0, bb0 = 0, bb1 = 0, mn = 0, rv = 0;
  float4 Q4 = make_float4(0, 0, 0, 0), Bl4 = Q4, H04 = Q4;
  float bb2[8];
  if (tid < 64) {
    ht0 = START[dbase];
    ht1 = START[dbase + 1];
    gs0 = ht0;
    gs1 = ht1;
    gg0 = ln_g[dbase];
    gg1 = ln_g[dbase + 1];
    bb0 = ln_b[dbase];
    bb1 = ln_b[dbase + 1];
    Q4 = *(const float4*)(Qc + colbase);
    Bl4 = *(const float4*)(Blnc + colbase);
    H04 = *(const float4*)(H0c + colbase);
#pragma unroll
    for (int q = 0; q < 4; ++q) {
      bb2[q] = b2[q * 512 + dbase];
      bb2[4 + q] = b2[q * 512 + dbase + 1];
    }
  }
  __syncthreads();  // weights staged

  for (int t = 0; t < SS; ++t) {
    // ---------- A-head: finalize step t-1 (owner lanes) -------------------
    if (t > 0 && tid < 64) {
      const int par9 = ((t - 1) & 1) << 9;
      const float* sp = st_sum + par9 + (on << 3);
      const float* qp = st_ss + par9 + (on << 3);
      float s = 0.f, ss = 0.f;
#pragma unroll
      for (int i = 0; i < 8; ++i) {
        s += cload(sp + i);
        ss += cload(qp + i);
      }
      float mean = s * (1.0f / DD);
      float var = ss * (1.0f / DD) - mean * mean;
      float rsv = rsqrtf(var + LN_EPS);
      mn = mean;
      rv = rsv;
      float hn0 = (z0 - mean) * rsv * gg0 + bb0;
      float hn1 = (z1 - mean) * rsv * gg1 + bb1;
      float m = mask[on * SS + (t - 1)];
      float* op =
          outseq + (size_t)on * SS * DD + (size_t)(t - 1) * DD + dbase;
      if (use_xt) {
        *(float2*)op = make_float2(hn0 * m, hn1 * m);  // output-only
      } else {
        cstore2(op, hn0 * m, hn1 * m);  // read cross-block in fallback
      }
      gs0 = m * hn0 + (1.0f - m) * gs0;
      gs1 = m * hn1 + (1.0f - m) * gs1;
      ht0 = hn0;
      ht1 = hn1;
    }
    if (b == 0) {  // zero stats parity t&1 (used by B(t) after barrier 1)
      const int parz9 = (t & 1) << 9;
      cstore(st_sum + parz9 + tid, 0.f);
      cstore(st_ss + parz9 + tid, 0.f);
    }
    // ---------- A waves: gemm1 partials -----------------------------------
    {
      const int h = lane >> 5;
      const int bl = lane & 31;
      float4 acc = make_float4(0.f, 0.f, 0.f, 0.f);
      if (w < 4) {
        if (t > 0) {  // z-part: k2 in [w*64, w*64+64), paired layout
          const float* ap = zT + (w << 13) + (bhalf << 6) + (bl << 1);
          const float* wp = W1s + (w << 10);  // k2*16
          for (int c0 = 0; c0 < 64; c0 += 32) {
            unsigned long long v[32];
#pragma unroll
            for (int j = 0; j < 32; ++j)
              v[j] = cload8(
                  (const unsigned long long*)(ap + ((c0 + j) << 7)));
#pragma unroll
            for (int j = 0; j < 32; ++j) {
              float2 zv = u2f2(v[j]);
              const float* wr = wp + ((c0 + j) << 4) + (h << 2);
              acc.x = fmaf(zv.x, wr[0], acc.x);
              acc.y = fmaf(zv.x, wr[1], acc.y);
              acc.z = fmaf(zv.x, wr[2], acc.z);
              acc.w = fmaf(zv.x, wr[3], acc.w);
              acc.x = fmaf(zv.y, wr[8], acc.x);
              acc.y = fmaf(zv.y, wr[9], acc.y);
              acc.z = fmaf(zv.y, wr[10], acc.z);
              acc.w = fmaf(zv.y, wr[11], acc.w);
            }
          }
        }
      } else {
        const int kxb = (w - 4) << 7;  // x K-slice base (0..384)
        const float* wp = W1s + ((512 + kxb) << 3);
        if (use_xt) {  // x-part: read-only prologue data, cached loads
          const float* xp =
              xT + (((size_t)t * DD + kxb) << 6) + (bhalf << 5) + bl;
          for (int c0 = 0; c0 < 128; c0 += 64) {
            float v[64];
#pragma unroll
            for (int j = 0; j < 64; ++j) v[j] = xp[(c0 + j) << 6];
#pragma unroll
            for (int j = 0; j < 64; ++j) {
              const float* wr = wp + ((c0 + j) << 3) + (h << 2);
              acc.x = fmaf(v[j], wr[0], acc.x);
              acc.y = fmaf(v[j], wr[1], acc.y);
              acc.z = fmaf(v[j], wr[2], acc.z);
              acc.w = fmaf(v[j], wr[3], acc.w);
            }
          }
        } else {
          const int n = (bhalf << 5) + bl;
          const float* op =
              outseq + (size_t)n * SS * DD + (size_t)t * DD + kxb;
          for (int c0 = 0; c0 < 128; c0 += 16) {
            float4 xv[4];
#pragma unroll
            for (int j = 0; j < 4; ++j)
              xv[j] = *(const float4*)(op + c0 + 4 * j);
#pragma unroll
            for (int j = 0; j < 16; ++j) {
              const float* wr = wp + ((c0 + j) << 3) + (h << 2);
              float x = ((const float*)xv)[j];
              acc.x = fmaf(x, wr[0], acc.x);
              acc.y = fmaf(x, wr[1], acc.y);
              acc.z = fmaf(x, wr[2], acc.z);
              acc.w = fmaf(x, wr[3], acc.w);
            }
          }
        }
      }
      pA4[w][lane] = acc;
    }
    __syncthreads();
    // ---------- A-tail: LN fold + gelu -> interT (paired, coherent) -------
    if (tid < 64) {
      float4 P = pA4[0][tid];
      float4 X = pA4[4][tid];
#pragma unroll
      for (int ww = 1; ww < 4; ++ww) {
        float4 p = pA4[ww][tid];
        P.x += p.x; P.y += p.y; P.z += p.z; P.w += p.w;
        float4 x4 = pA4[ww + 4][tid];
        X.x += x4.x; X.y += x4.y; X.z += x4.z; X.w += x4.w;
      }
      float4 o;
      if (t > 0) {
        float c1 = -rv * mn;
        o.x = fmaf(rv, P.x, fmaf(c1, Q4.x, Bl4.x)) + X.x;
        o.y = fmaf(rv, P.y, fmaf(c1, Q4.y, Bl4.y)) + X.y;
        o.z = fmaf(rv, P.z, fmaf(c1, Q4.z, Bl4.z)) + X.z;
        o.w = fmaf(rv, P.w, fmaf(c1, Q4.w, Bl4.w)) + X.w;
      } else {
        o.x = H04.x + X.x;
        o.y = H04.y + X.y;
        o.z = H04.z + X.z;
        o.w = H04.w + X.w;
      }
      // paired layout: interT[(c>>1)*128 + n*2 + (c&1)]
      cstore2(interT + ((colbase >> 1) << 7) + (on << 1), geluf(o.x),
              geluf(o.y));
      cstore2(interT + (((colbase >> 1) + 1) << 7) + (on << 1), geluf(o.z),
              geluf(o.w));
    }
    gbar(sync, ++ep);  // barrier 1: interT visible
    // ---------- B waves: gemm2 partials (paired coherent loads) -----------
    {
      const int h = lane >> 5;
      const int bl = lane & 31;
      float4 accL = make_float4(0.f, 0.f, 0.f, 0.f);
      float4 accH = make_float4(0.f, 0.f, 0.f, 0.f);
      const float* w2 = W2s + (w << 11);  // k2*32
      const float* ip = interT + (w << 13) + (bhalf << 6) + (bl << 1);
      for (int c0 = 0; c0 < 64; c0 += 32) {
        unsigned long long v[32];
#pragma unroll
        for (int j = 0; j < 32; ++j)
          v[j] = cload8((const unsigned long long*)(ip + ((c0 + j) << 7)));
#pragma unroll
        for (int j = 0; j < 32; ++j) {
          float2 iv = u2f2(v[j]);
          const float* wr = w2 + ((c0 + j) << 5) + (h << 3);
          accL.x = fmaf(iv.x, wr[0], accL.x);
          accL.y = fmaf(iv.x, wr[1], accL.y);
          accL.z = fmaf(iv.x, wr[2], accL.z);
          accL.w = fmaf(iv.x, wr[3], accL.w);
          accH.x = fmaf(iv.x, wr[4], accH.x);
          accH.y = fmaf(iv.x, wr[5], accH.y);
          accH.z = fmaf(iv.x, wr[6], accH.z);
          accH.w = fmaf(iv.x, wr[7], accH.w);
          accL.x = fmaf(iv.y, wr[16], accL.x);
          accL.y = fmaf(iv.y, wr[17], accL.y);
          accL.z = fmaf(iv.y, wr[18], accL.z);
          accL.w = fmaf(iv.y, wr[19], accL.w);
          accH.x = fmaf(iv.y, wr[20], accH.x);
          accH.y = fmaf(iv.y, wr[21], accH.y);
          accH.z = fmaf(iv.y, wr[22], accH.z);
          accH.w = fmaf(iv.y, wr[23], accH.w);
        }
      }
      pB4[w][lane][0] = accL;
      pB4[w][lane][1] = accH;
    }
    __syncthreads();
    // ---------- B-tail: gates -> z (paired, coherent), stats atomics ------
    if (tid < 64) {
      float4 lo = pB4[0][tid][0];
      float4 hi = pB4[0][tid][1];
#pragma unroll
      for (int ww = 1; ww < 8; ++ww) {
        float4 p = pB4[ww][tid][0];
        lo.x += p.x; lo.y += p.y; lo.z += p.z; lo.w += p.w;
        float4 q = pB4[ww][tid][1];
        hi.x += q.x; hi.y += q.y; hi.z += q.z; hi.w += q.w;
      }
      lo.x += bb2[0]; lo.y += bb2[1]; lo.z += bb2[2]; lo.w += bb2[3];
      hi.x += bb2[4]; hi.y += bb2[5]; hi.z += bb2[6]; hi.w += bb2[7];
      float x0, x1;
      if (use_xt) {
        x0 = xT[((size_t)t * DD + dbase) * 64 + on];
        x1 = xT[((size_t)t * DD + dbase + 1) * 64 + on];
      } else {
        float2 x2 = *(const float2*)(outseq + (size_t)on * SS * DD +
                                     (size_t)t * DD + dbase);
        x0 = x2.x;
        x1 = x2.y;
      }
      // lo = dim dbase (q0..q3), hi = dim dbase+1 (q0..q3)
      z0 = sigf(lo.x) * ht0 + sigf(lo.y) * x0 + sigf(lo.z) * lo.w;
      z1 = sigf(hi.x) * ht1 + sigf(hi.y) * x1 + sigf(hi.z) * hi.w;
      cstore2(zT + ((dbase >> 1) << 7) + (on << 1), z0, z1);
      const int par9 = (t & 1) << 9;
      const int slot = bcol & 7;
      atomicAdd(st_sum + par9 + (on << 3) + slot, z0 + z1);
      atomicAdd(st_ss + par9 + (on << 3) + slot, z0 * z0 + z1 * z1);
    }
    gbar(sync, ++ep);  // barrier 2: z + stats visible
  }
  // ---------- flush step 511 ----------
  if (tid < 64) {
    const int par9 = ((SS - 1) & 1) << 9;
    const float* sp = st_sum + par9 + (on << 3);
    const float* qp = st_ss + par9 + (on << 3);
    float s = 0.f, ss = 0.f;
#pragma unroll
    for (int i = 0; i < 8; ++i) {
      s += cload(sp + i);
      ss += cload(qp + i);
    }
    float mean = s * (1.0f / DD);
    float var = ss * (1.0f / DD) - mean * mean;
    float rsv = rsqrtf(var + LN_EPS);
    float hn0 = (z0 - mean) * rsv * gg0 + bb0;
    float hn1 = (z1 - mean) * rsv * gg1 + bb1;
    float m = mask[on * SS + (SS - 1)];
    *(float2*)(outseq + (size_t)on * SS * DD + (size_t)(SS - 1) * DD +
               dbase) = make_float2(hn0 * m, hn1 * m);
    gs0 = m * hn0 + (1.0f - m) * gs0;
    gs1 = m * hn1 + (1.0f - m) * gs1;
    *(float2*)(gsout + on * DD + dbase) = make_float2(gs0, gs1);
  }
}

// ---------------- host ----------------------------------------------------
extern "C" void kernel_launch(void* const* d_in, const int* in_sizes, int n_in,
                              void* d_out, int out_size, void* d_ws,
                              size_t ws_size, hipStream_t stream) {
  const float* seq = (const float*)d_in[0];
  const float* mask = (const float*)d_in[1];
  const float* START = (const float*)d_in[2];
  const float* W_init = (const float*)d_in[3];
  const float* b_init = (const float*)d_in[4];
  const float* W1 = (const float*)d_in[5];
  const float* b1 = (const float*)d_in[6];
  const float* W2 = (const float*)d_in[7];
  const float* b2 = (const float*)d_in[8];
  const float* ln_g = (const float*)d_in[9];
  const float* ln_b = (const float*)d_in[10];

  float* out = (float*)d_out;
  float* outseq = out;
  float* gsout = out + (size_t)NB * SS * DD;

  float* W1p = (float*)d_ws;              // 1,048,576
  float* W2p = W1p + 1048576;             // 2,097,152
  float* interT = W2p + 2097152;          // 65,536 (paired [512][64][2])
  float* zT = interT + 65536;             // 32,768 (paired [256][64][2])
  float* st_sum = zT + 32768;             // 4,096 (uses [2][64][8])
  float* st_ss = st_sum + 4096;           // 4,096
  float* Qc = st_ss + 4096;               // 1,024
  float* Blnc = Qc + 1024;                // 1,024
  float* H0c = Blnc + 1024;               // 1,024
  unsigned* syncw = (unsigned*)(H0c + 1024);  // 1,024 u32
  float* xT = (float*)(syncw + 1024);     // 16,777,216 (optional)
  const size_t base_floats = 1048576 + 2097152 + 65536 + 32768 + 4096 + 4096 +
                             1024 + 1024 + 1024 + 1024;
  const int use_xt =
      (ws_size >= (base_floats + (size_t)16777216) * 4) ? 1 : 0;

  dim3 ga(DD / 64, (NB * SS) / 64);
  k_gemm_init<<<ga, 256, 0, stream>>>(seq, mask, W_init, b_init, outseq);
  k_ln_rows<<<NB * SS, 256, 0, stream>>>(outseq, mask, ln_g, ln_b);
  if (use_xt) {
    k_xt<<<dim3(SS, 8), 256, 0, stream>>>(outseq, xT);
  }
  k_pack1<<<4096, 256, 0, stream>>>(W1, ln_g, W1p);
  k_pack2<<<8192, 256, 0, stream>>>(W2, W2p);
  k_cols<<<8, 128, 0, stream>>>(W1, b1, ln_g, ln_b, START, Qc, Blnc, H0c,
                                syncw);

  scan_kernel<<<256, 512, 0, stream>>>(outseq, gsout, mask, START, W1p, W2p,
                                       b2, ln_g, ln_b, Qc, Blnc, H0c, interT,
                                       zT, st_sum, st_ss, xT, syncw, use_xt);
}